// Round 3
// baseline (1163.503 us; speedup 1.0000x reference)
//
#include <hip/hip_runtime.h>

typedef unsigned short u16;
typedef __attribute__((ext_vector_type(8))) short bf16x8;
typedef __attribute__((ext_vector_type(4))) float f32x4;

__device__ __forceinline__ u16 f2bf(float f) {
  union { float f; unsigned u; } v; v.f = f;
  unsigned u = v.u;
  u += 0x7fffu + ((u >> 16) & 1u);
  return (u16)(u >> 16);
}

__device__ __forceinline__ void gll16(const void* g, void* l) {
  __builtin_amdgcn_global_load_lds(
      (const __attribute__((address_space(1))) void*)g,
      (__attribute__((address_space(3))) void*)l, 16, 0, 0);
}

// ---------------------------------------------------------------------------
// P1: x[b][c][n] f32 -> xt[b][n][c] bf16  (C=512, N=1600), both inputs.
// 64x64 tile; coalesced f32 reads, ushort4 (8B) stores.
// ---------------------------------------------------------------------------
__global__ __launch_bounds__(256) void transp_cast_x2(const float* __restrict__ ex,
                                                      const float* __restrict__ qu,
                                                      u16* __restrict__ xte,
                                                      u16* __restrict__ xtq) {
  __shared__ float t[64][65];
  int z = blockIdx.z;
  int b = z & 15;
  const float* xb = (z < 16 ? ex : qu) + (size_t)b * 819200;
  u16* xtb = (z < 16 ? xte : xtq) + (size_t)b * 819200;
  int n0 = blockIdx.x * 64, c0 = blockIdx.y * 64;
  int n = threadIdx.x & 63, cq = threadIdx.x >> 6;
#pragma unroll
  for (int r = 0; r < 16; r++) {
    int c = cq + r * 4;
    t[c][n] = xb[(size_t)(c0 + c) * 1600 + n0 + n];
  }
  __syncthreads();
  int cg = threadIdx.x & 15, nr = threadIdx.x >> 4;
#pragma unroll
  for (int r = 0; r < 4; r++) {
    int nn = nr + r * 16;
    int c = cg * 4;
    ushort4 v;
    v.x = f2bf(t[c + 0][nn]);
    v.y = f2bf(t[c + 1][nn]);
    v.z = f2bf(t[c + 2][nn]);
    v.w = f2bf(t[c + 3][nn]);
    *(ushort4*)&xtb[(size_t)(n0 + nn) * 512 + c0 + c] = v;
  }
}

// P2: cast w_e / w_q (256x512 each) to bf16
__global__ void cast_w(const float* __restrict__ we, const float* __restrict__ wq,
                       u16* __restrict__ oe, u16* __restrict__ oq) {
  int i = blockIdx.x * 256 + threadIdx.x;
  oe[i] = f2bf(we[i]);
  oq[i] = f2bf(wq[i]);
}

// P3: w[o][c][ky][kx] f32 -> wr[o][t*512+c] bf16; thread per (o,c),
// 9 contiguous f32 reads, coalesced u16 writes per tap.
__global__ void repack_wc2(const float* __restrict__ w1, const float* __restrict__ w2,
                           u16* __restrict__ o1, u16* __restrict__ o2) {
  const float* w = blockIdx.y ? w2 : w1;
  u16* wr = blockIdx.y ? o2 : o1;
  int idx = blockIdx.x * 256 + threadIdx.x;  // 262144 = o*512+c
  int o = idx >> 9, c = idx & 511;
  const float* src = w + (size_t)idx * 9;
  float v[9];
#pragma unroll
  for (int t = 0; t < 9; t++) v[t] = src[t];
#pragma unroll
  for (int t = 0; t < 9; t++) wr[o * 4608 + t * 512 + c] = f2bf(v[t]);
}

// P4a: zero Zrow/Zcol (204800 B = 12800 uint4), grid 50
__global__ void zero_small(uint4* __restrict__ p) {
  uint4 z; z.x = 0; z.y = 0; z.z = 0; z.w = 0;
  p[blockIdx.x * 256 + threadIdx.x] = z;
}

// P4b: zero only the 1-px border of the padded att layouts. 164 border px per
// 42x42 image, 512 u16 each. grid (41, 16, 2), 4 px per block.
__global__ void zero_border(u16* __restrict__ att_e, u16* __restrict__ att_q) {
  u16* base = (blockIdx.z ? att_q : att_e) + (size_t)blockIdx.y * 903168;
  int k = blockIdx.x * 4 + (threadIdx.x >> 6);
  int y, x;
  if (k < 42) { y = 0; x = k; }
  else if (k < 84) { y = 41; x = k - 42; }
  else { int r = k - 84; y = 1 + (r >> 1); x = (r & 1) ? 41 : 0; }
  int lane = threadIdx.x & 63;
  uint4 z; z.x = 0; z.y = 0; z.z = 0; z.w = 0;
  *(uint4*)(base + (size_t)(y * 42 + x) * 512 + lane * 8) = z;
}

// ---------------------------------------------------------------------------
// Generic A*B^T bf16 GEMM, 128x128 tile, BK=64, XOR-swizzled LDS,
// dual problem sets via blockIdx.z. MODE 0: C[i*N+j] bf16. MODE 2: padded
// pixel layout bf16.
// ---------------------------------------------------------------------------
template <int MODE>
__global__ __launch_bounds__(256, 4) void gemm_bt64(
    const u16* __restrict__ A, const u16* __restrict__ B, u16* __restrict__ C,
    const u16* __restrict__ A2, const u16* __restrict__ B2, u16* __restrict__ C2,
    int M, int N, int K, long sA, long sB, long sC) {
  __shared__ u16 lds_a[128 * 64];
  __shared__ u16 lds_b[128 * 64];
  int tid = threadIdx.x;
  int z = blockIdx.z, b = z & 15;
  const u16* Ab = (z < 16 ? A : A2) + (size_t)b * sA;
  const u16* Bb = (z < 16 ? B : B2) + (size_t)b * sB;
  u16* Cb = (z < 16 ? C : C2) + (size_t)b * sC;
  int m0 = blockIdx.x * 128, n0 = blockIdx.y * 128;

  int rsub = tid >> 3;
  int gch = (tid & 7) ^ (rsub & 7);
  long Kb = (long)K * 2;
  const char* pa[4];
  const char* pb[4];
#pragma unroll
  for (int c = 0; c < 4; c++) {
    int ra = m0 + 32 * c + rsub; ra = ra < M ? ra : M - 1;
    int rb = n0 + 32 * c + rsub; rb = rb < N ? rb : N - 1;
    pa[c] = (const char*)Ab + (long)ra * Kb + gch * 16;
    pb[c] = (const char*)Bb + (long)rb * Kb + gch * 16;
  }

  const f32x4 fzero = {0.f, 0.f, 0.f, 0.f};
  f32x4 acc[4][4];
#pragma unroll
  for (int mi = 0; mi < 4; mi++)
#pragma unroll
    for (int ni = 0; ni < 4; ni++) acc[mi][ni] = fzero;

  int wid = tid >> 6, lane = tid & 63;
  int wm = wid & 1, wn = wid >> 1;
  int lrow = lane & 15, lquad = lane >> 4;
  int sl = lrow & 7;

  int ksteps = K >> 6;
  for (int ks = 0; ks < ksteps; ks++) {
#pragma unroll
    for (int c = 0; c < 4; c++) {
      gll16(pa[c], (char*)lds_a + c * 4096 + tid * 16);
      gll16(pb[c], (char*)lds_b + c * 4096 + tid * 16);
      pa[c] += 128; pb[c] += 128;
    }
    __syncthreads();
#pragma unroll
    for (int k2 = 0; k2 < 2; k2++) {
      int sel = ((k2 << 2) | lquad) ^ sl;
      bf16x8 bv[4];
#pragma unroll
      for (int ni = 0; ni < 4; ni++) {
        int rowb = wn * 64 + ni * 16 + lrow;
        bv[ni] = *(const bf16x8*)((const char*)lds_b + rowb * 128 + sel * 16);
      }
#pragma unroll
      for (int mi = 0; mi < 4; mi++) {
        int rowa = wm * 64 + mi * 16 + lrow;
        bf16x8 av = *(const bf16x8*)((const char*)lds_a + rowa * 128 + sel * 16);
#pragma unroll
        for (int ni = 0; ni < 4; ni++)
          acc[mi][ni] =
              __builtin_amdgcn_mfma_f32_16x16x32_bf16(av, bv[ni], acc[mi][ni], 0, 0, 0);
      }
    }
    __syncthreads();
  }

#pragma unroll
  for (int mi = 0; mi < 4; mi++) {
#pragma unroll
    for (int r = 0; r < 4; r++) {
      int i = m0 + wm * 64 + mi * 16 + lquad * 4 + r;
      if (i >= M) continue;
#pragma unroll
      for (int ni = 0; ni < 4; ni++) {
        int j = n0 + wn * 64 + ni * 16 + lrow;
        if (j >= N) continue;
        float v = acc[mi][ni][r];
        if (MODE == 2) {
          int y = i / 40, x = i - y * 40;
          Cb[(size_t)((y + 1) * 42 + (x + 1)) * 512 + j] = f2bf(v);
        } else {
          Cb[(size_t)i * N + j] = f2bf(v);
        }
      }
    }
  }
}

// ---------------------------------------------------------------------------
// K2: E = exp(ecorr * qcorr^T) with fused E/ET/Zrow/Zcol epilogue.
// ---------------------------------------------------------------------------
__global__ __launch_bounds__(256) void gemm_corr_exp(
    const u16* __restrict__ A, const u16* __restrict__ B, u16* __restrict__ E,
    u16* __restrict__ ET, float* __restrict__ Zrow, float* __restrict__ Zcol) {
  __shared__ u16 lds_a[128 * 64];
  __shared__ u16 lds_b[128 * 64];
  int tid = threadIdx.x;
  int b = blockIdx.z;
  const u16* Ab = A + (size_t)b * 409600;
  const u16* Bb = B + (size_t)b * 409600;
  u16* Eb = E + (size_t)b * 2560000;
  u16* ETb = ET + (size_t)b * 2560000;
  int m0 = blockIdx.x * 128, n0 = blockIdx.y * 128;

  int rsub = tid >> 3;
  int gch = (tid & 7) ^ (rsub & 7);
  const char* pa[4];
  const char* pb[4];
#pragma unroll
  for (int c = 0; c < 4; c++) {
    int ra = m0 + 32 * c + rsub; ra = ra < 1600 ? ra : 1599;
    int rb = n0 + 32 * c + rsub; rb = rb < 1600 ? rb : 1599;
    pa[c] = (const char*)(Ab + (size_t)ra * 256) + gch * 16;
    pb[c] = (const char*)(Bb + (size_t)rb * 256) + gch * 16;
  }

  const f32x4 fzero = {0.f, 0.f, 0.f, 0.f};
  f32x4 acc[4][4];
#pragma unroll
  for (int mi = 0; mi < 4; mi++)
#pragma unroll
    for (int ni = 0; ni < 4; ni++) acc[mi][ni] = fzero;

  int wid = tid >> 6, lane = tid & 63;
  int wm = wid & 1, wn = wid >> 1;
  int lrow = lane & 15, lquad = lane >> 4;
  int sl = lrow & 7;

  for (int ks = 0; ks < 4; ks++) {
#pragma unroll
    for (int c = 0; c < 4; c++) {
      gll16(pa[c], (char*)lds_a + c * 4096 + tid * 16);
      gll16(pb[c], (char*)lds_b + c * 4096 + tid * 16);
      pa[c] += 128; pb[c] += 128;
    }
    __syncthreads();
#pragma unroll
    for (int k2 = 0; k2 < 2; k2++) {
      int sel = ((k2 << 2) | lquad) ^ sl;
      bf16x8 bv[4];
#pragma unroll
      for (int ni = 0; ni < 4; ni++) {
        int rowb = wn * 64 + ni * 16 + lrow;
        bv[ni] = *(const bf16x8*)((const char*)lds_b + rowb * 128 + sel * 16);
      }
#pragma unroll
      for (int mi = 0; mi < 4; mi++) {
        int rowa = wm * 64 + mi * 16 + lrow;
        bf16x8 av = *(const bf16x8*)((const char*)lds_a + rowa * 128 + sel * 16);
#pragma unroll
        for (int ni = 0; ni < 4; ni++)
          acc[mi][ni] =
              __builtin_amdgcn_mfma_f32_16x16x32_bf16(av, bv[ni], acc[mi][ni], 0, 0, 0);
      }
    }
    __syncthreads();
  }

  // ---- fused epilogue: exp, E store, ET store (LDS transpose), Z sums ----
  const int TS = 136;
  u16* T = lds_a;
  float colacc[4] = {0.f, 0.f, 0.f, 0.f};
#pragma unroll
  for (int s = 0; s < 4; s++) {
    if (wm == (s >> 1)) {
      int smi0 = (s & 1) * 2;
#pragma unroll
      for (int mi2 = 0; mi2 < 2; mi2++) {
        int mi = smi0 + mi2;
        float rowp[4] = {0.f, 0.f, 0.f, 0.f};
#pragma unroll
        for (int ni = 0; ni < 4; ni++) {
          int j = n0 + wn * 64 + ni * 16 + lrow;
          bool jv = j < 1600;
#pragma unroll
          for (int r = 0; r < 4; r++) {
            int i = m0 + wm * 64 + mi * 16 + lquad * 4 + r;
            float e = __expf(acc[mi][ni][r]);
            T[(mi2 * 16 + lquad * 4 + r) * TS + wn * 64 + ni * 16 + lrow] = f2bf(e);
            rowp[r] += jv ? e : 0.f;
            colacc[ni] += (i < 1600) ? e : 0.f;
          }
        }
#pragma unroll
        for (int r = 0; r < 4; r++) {
          float v = rowp[r];
          v += __shfl_xor(v, 1);
          v += __shfl_xor(v, 2);
          v += __shfl_xor(v, 4);
          v += __shfl_xor(v, 8);
          int i = m0 + wm * 64 + mi * 16 + lquad * 4 + r;
          if (lrow == 0 && i < 1600) atomicAdd(&Zrow[b * 1600 + i], v);
        }
      }
    }
    __syncthreads();
#pragma unroll
    for (int p = 0; p < 2; p++) {
      int jj = tid + p * 256;
      int ml = jj >> 4, n8 = jj & 15;
      int gi = m0 + s * 32 + ml, gj = n0 + n8 * 8;
      if (gi < 1600 && gj < 1600)
        *(uint4*)(Eb + (size_t)gi * 1600 + gj) = *(const uint4*)&T[ml * TS + n8 * 8];
    }
#pragma unroll
    for (int p = 0; p < 4; p++) {
      int jj = tid + p * 256;
      int n = jj >> 3, m4 = jj & 7;
      int gm = m0 + s * 32 + m4 * 4, gn = n0 + n;
      if (gn < 1600 && gm < 1600) {
        ushort4 v;
        v.x = T[(m4 * 4 + 0) * TS + n];
        v.y = T[(m4 * 4 + 1) * TS + n];
        v.z = T[(m4 * 4 + 2) * TS + n];
        v.w = T[(m4 * 4 + 3) * TS + n];
        *(ushort4*)(ETb + (size_t)gn * 1600 + gm) = v;
      }
    }
    __syncthreads();
  }
#pragma unroll
  for (int ni = 0; ni < 4; ni++) {
    float v = colacc[ni];
    v += __shfl_xor(v, 16);
    v += __shfl_xor(v, 32);
    int j = n0 + wn * 64 + ni * 16 + lrow;
    if (lquad == 0 && j < 1600) atomicAdd(&Zcol[b * 1600 + j], v);
  }
}

// K3: out = bf16(x / Z[pixel]), float4/ushort4 vectorized
__global__ void scale_div4(const float* __restrict__ ex, const float* __restrict__ qu,
                           const float* __restrict__ Zcol, const float* __restrict__ Zrow,
                           u16* __restrict__ ebf, u16* __restrict__ qbf) {
  const float* x; const float* Z; u16* o;
  if (blockIdx.y == 0) { x = ex; Z = Zcol; o = ebf; }
  else { x = qu; Z = Zrow; o = qbf; }
  size_t e = ((size_t)blockIdx.x * 256 + threadIdx.x) * 4;  // 13,107,200 per set
  int b = (int)(e / 819200);
  int i = (int)(e % 1600);
  float4 x4 = *(const float4*)(x + e);
  float4 z4 = *(const float4*)(Z + b * 1600 + i);
  ushort4 v;
  v.x = f2bf(x4.x / z4.x);
  v.y = f2bf(x4.y / z4.y);
  v.z = f2bf(x4.z / z4.z);
  v.w = f2bf(x4.w / z4.w);
  *(ushort4*)(o + e) = v;
}

// ---------------------------------------------------------------------------
// K5: both 3x3 convs as A*B^T GEMM, BK=64, tap-structured K loop.
// ---------------------------------------------------------------------------
__global__ __launch_bounds__(256, 4) void conv_gemm64(
    const u16* __restrict__ W1, const u16* __restrict__ ATT1,
    const u16* __restrict__ W2, const u16* __restrict__ ATT2,
    float* __restrict__ out) {
  __shared__ u16 lds_a[128 * 64];
  __shared__ u16 lds_b[128 * 64];
  int tid = threadIdx.x;
  int z = blockIdx.z, b = z & 15, sel2 = z >> 4;
  const u16* W = sel2 ? W2 : W1;
  const u16* attb = (sel2 ? ATT2 : ATT1) + (size_t)b * 903168;
  float* outb = out + (size_t)b * 1638400 + (size_t)(sel2 ? 512 : 0) * 1600;
  int p0 = blockIdx.x * 128, o0 = blockIdx.y * 128;

  int rsub = tid >> 3;
  int gch = (tid & 7) ^ (rsub & 7);
  const char* pa[4];
  const char* pb[4];
#pragma unroll
  for (int c = 0; c < 4; c++) {
    int ro = o0 + 32 * c + rsub;
    pa[c] = (const char*)(W + (size_t)ro * 4608) + gch * 16;
    int p = p0 + 32 * c + rsub; p = p < 1600 ? p : 1599;
    int y = p / 40, x = p - y * 40;
    pb[c] = (const char*)(attb + (size_t)(y * 42 + x) * 512) + gch * 16;
  }

  const f32x4 fzero = {0.f, 0.f, 0.f, 0.f};
  f32x4 acc[4][4];
#pragma unroll
  for (int mi = 0; mi < 4; mi++)
#pragma unroll
    for (int ni = 0; ni < 4; ni++) acc[mi][ni] = fzero;

  int wid = tid >> 6, lane = tid & 63;
  int wm = wid & 1, wn = wid >> 1;
  int lrow = lane & 15, lquad = lane >> 4;
  int sl = lrow & 7;

  int tapbyte = 0, dxc = 0;
  for (int t = 0; t < 9; t++) {
#pragma unroll 2
    for (int kc = 0; kc < 8; kc++) {
#pragma unroll
      for (int c = 0; c < 4; c++) {
        gll16(pa[c], (char*)lds_a + c * 4096 + tid * 16);
        gll16(pb[c] + tapbyte + kc * 128, (char*)lds_b + c * 4096 + tid * 16);
        pa[c] += 128;
      }
      __syncthreads();
#pragma unroll
      for (int k2 = 0; k2 < 2; k2++) {
        int sel = ((k2 << 2) | lquad) ^ sl;
        bf16x8 bv[4];
#pragma unroll
        for (int ni = 0; ni < 4; ni++) {
          int rowb = wn * 64 + ni * 16 + lrow;
          bv[ni] = *(const bf16x8*)((const char*)lds_b + rowb * 128 + sel * 16);
        }
#pragma unroll
        for (int mi = 0; mi < 4; mi++) {
          int rowa = wm * 64 + mi * 16 + lrow;
          bf16x8 av = *(const bf16x8*)((const char*)lds_a + rowa * 128 + sel * 16);
#pragma unroll
          for (int ni = 0; ni < 4; ni++)
            acc[mi][ni] = __builtin_amdgcn_mfma_f32_16x16x32_bf16(av, bv[ni],
                                                                  acc[mi][ni], 0, 0, 0);
        }
      }
      __syncthreads();
    }
    dxc++;
    tapbyte += 1024;
    if (dxc == 3) { dxc = 0; tapbyte += 39 * 1024; }
  }

#pragma unroll
  for (int mi = 0; mi < 4; mi++) {
#pragma unroll
    for (int r = 0; r < 4; r++) {
      int o = o0 + wm * 64 + mi * 16 + lquad * 4 + r;
#pragma unroll
      for (int ni = 0; ni < 4; ni++) {
        int p = p0 + wn * 64 + ni * 16 + lrow;
        if (p < 1600) outb[(size_t)o * 1600 + p] = acc[mi][ni][r];
      }
    }
  }
}

// ---------------------------------------------------------------------------
extern "C" void kernel_launch(void* const* d_in, const int* in_sizes, int n_in,
                              void* d_out, int out_size, void* d_ws, size_t ws_size,
                              hipStream_t stream) {
  const float* ex = (const float*)d_in[0];
  const float* qu = (const float*)d_in[1];
  const float* w_e = (const float*)d_in[2];
  const float* w_q = (const float*)d_in[3];
  const float* w_c1 = (const float*)d_in[4];
  const float* w_c2 = (const float*)d_in[5];
  float* out = (float*)d_out;
  char* ws = (char*)d_ws;

  u16* E     = (u16*)(ws + 0L);
  u16* ET    = (u16*)(ws + 81920000L);
  u16* xt_e  = (u16*)(ws + 163840000L);
  u16* xt_q  = (u16*)(ws + 190054400L);
  u16* ecorr = (u16*)(ws + 216268800L);
  u16* qcorr = (u16*)(ws + 229376000L);
  u16* att_e = (u16*)(ws + 242483200L);
  u16* att_q = (u16*)(ws + 271384576L);
  float* Zrow = (float*)(ws + 300285952L);
  float* Zcol = (float*)(ws + 300388352L);
  u16* w_ebf = (u16*)(ws + 300490752L);
  u16* w_qbf = (u16*)(ws + 300752896L);
  u16* wr1   = (u16*)(ws + 301015040L);
  u16* wr2   = (u16*)(ws + 305733632L);

  // prep
  transp_cast_x2<<<dim3(25, 8, 32), 256, 0, stream>>>(ex, qu, xt_e, xt_q);
  cast_w<<<dim3(512), 256, 0, stream>>>(w_e, w_q, w_ebf, w_qbf);
  repack_wc2<<<dim3(1024, 2), 256, 0, stream>>>(w_c1, w_c2, wr1, wr2);
  zero_small<<<dim3(50), 256, 0, stream>>>((uint4*)Zrow);
  zero_border<<<dim3(41, 16, 2), 256, 0, stream>>>(att_e, att_q);

  // K1: corr[b][n][o] = sum_c xt[n,c] * w[o,c]
  gemm_bt64<0><<<dim3(13, 2, 32), 256, 0, stream>>>(
      xt_e, w_ebf, ecorr, xt_q, w_qbf, qcorr, 1600, 256, 512, 819200L, 0L, 409600L);

  // K2: E/ET/Zrow/Zcol fused
  gemm_corr_exp<<<dim3(13, 13, 16), 256, 0, stream>>>(ecorr, qcorr, E, ET, Zrow, Zcol);

  // K3
  u16* ebf = xt_e;
  u16* qbf = xt_q;
  scale_div4<<<dim3(12800, 2), 256, 0, stream>>>(ex, qu, Zcol, Zrow, ebf, qbf);

  // K4
  gemm_bt64<2><<<dim3(13, 4, 32), 256, 0, stream>>>(
      E, ebf, att_q, ET, qbf, att_e, 1600, 512, 1600, 2560000L, 819200L, 903168L);

  // K5
  conv_gemm64<<<dim3(13, 4, 32), 256, 0, stream>>>(wr1, att_e, wr2, att_q, out);
}